// Round 12
// baseline (617.668 us; speedup 1.0000x reference)
//
#include <hip/hip_runtime.h>
#include <math.h>

namespace {

constexpr int kN = 1024;
constexpr int kD = 128;
constexpr int kBH = 64;
constexpr int IT = 64;     // i rows per block
constexpr int JT = 64;     // j cols per tile
constexpr int NTH = 1024;  // 16 waves
constexpr int SI = 136;    // i-side LDS row stride (bf16)
constexpr int SPT = 72;    // Pre bounce stride

constexpr float INV2SD = 0.04419417382415922f;  // 1/(2*sqrt(128))
constexpr float INVSD  = 0.08838834764831843f;  // 1/sqrt(128)
constexpr float TWOA   = 2.0f + 1e-5f;

// ws layout (u16 region then f32 region)
constexpr size_t AR = (size_t)kN * kD;
constexpr size_t BHU = 7 * AR;
constexpr size_t WS_U16 = (size_t)kBH * BHU;
constexpr size_t FOFF = WS_U16 / 2;
constexpr int KBN = kBH * kN;
constexpr int A_QH = 0, A_SQ = 1, A_QR = 2, A_KH = 3, A_SK = 4, A_KR = 5, A_VT = 6;

typedef __attribute__((ext_vector_type(8))) short s16x8;
typedef __attribute__((ext_vector_type(4))) short s16x4;
typedef __attribute__((ext_vector_type(4))) float f32x4;

__device__ __forceinline__ unsigned short f2bf(float f) {
  unsigned u = __float_as_uint(f);
  u += 0x7fffu + ((u >> 16) & 1u);   // RNE
  return (unsigned short)(u >> 16);
}
__device__ __forceinline__ float bf2f(unsigned short b) {
  return __uint_as_float(((unsigned)b) << 16);
}
__device__ __forceinline__ float sigm(float x) { return 1.0f / (1.0f + __expf(-x)); }

// ============================ prep kernel ============================
__global__ __launch_bounds__(256, 2)
void cpka_prep(const float* __restrict__ q, const float* __restrict__ k,
               const float* __restrict__ v, unsigned short* __restrict__ wsu,
               float* __restrict__ wsf) {
  const int blk = blockIdx.x;
  const int bh = blk >> 4;
  const int r0 = (blk & 15) * 64;
  const int t = threadIdx.x;
  unsigned short* bhp = wsu + (size_t)bh * BHU;
  const size_t base = ((size_t)bh * kN + r0) * kD;

  __shared__ unsigned short Vb[64 * 132];

#pragma unroll
  for (int pass = 0; pass < 2; ++pass) {
    const float* src = (pass == 0 ? q : k) + base;
    const int aH = (pass == 0) ? A_QH : A_KH;
    const int aS = (pass == 0) ? A_SQ : A_SK;
    const int aR = (pass == 0) ? A_QR : A_KR;
    const int sN = (pass == 0) ? 0 : 1;
    const int sS = (pass == 0) ? 2 : 3;
#pragma unroll 2
    for (int it = 0; it < 8; ++it) {
      const int g = it * 1024 + t * 4;
      const int row = g >> 7;
      const float4 a = *(const float4*)(src + g);
      float ss = a.x * a.x + a.y * a.y + a.z * a.z + a.w * a.w;
      ss += __shfl_xor(ss, 1); ss += __shfl_xor(ss, 2); ss += __shfl_xor(ss, 4);
      ss += __shfl_xor(ss, 8); ss += __shfl_xor(ss, 16);
      const float rn = rsqrtf(ss);
      const float x0 = a.x * rn, x1 = a.y * rn, x2 = a.z * rn, x3 = a.w * rn;
      s16x4 hb; hb[0] = f2bf(x0); hb[1] = f2bf(x1); hb[2] = f2bf(x2); hb[3] = f2bf(x3);
      *(s16x4*)&bhp[aH * AR + (size_t)r0 * kD + g] = hb;
      const float g0 = sigm(x0), g1 = sigm(x1), g2 = sigm(x2), g3 = sigm(x3);
      float sg = g0 + g1 + g2 + g3;
      sg += __shfl_xor(sg, 1); sg += __shfl_xor(sg, 2); sg += __shfl_xor(sg, 4);
      sg += __shfl_xor(sg, 8); sg += __shfl_xor(sg, 16);
      s16x4 sb; sb[0] = f2bf(g0); sb[1] = f2bf(g1); sb[2] = f2bf(g2); sb[3] = f2bf(g3);
      *(s16x4*)&bhp[aS * AR + (size_t)r0 * kD + g] = sb;
      s16x4 rb; rb[0] = f2bf(a.x); rb[1] = f2bf(a.y); rb[2] = f2bf(a.z); rb[3] = f2bf(a.w);
      *(s16x4*)&bhp[aR * AR + (size_t)r0 * kD + g] = rb;
      if ((t & 31) == 0) {
        wsf[sN * KBN + bh * kN + r0 + row] = ss;
        wsf[sS * KBN + bh * kN + r0 + row] = sg;
      }
    }
  }

#pragma unroll 2
  for (int it = 0; it < 8; ++it) {
    const int g = it * 1024 + t * 4;
    const int row = g >> 7, col = g & 127;
    const float4 a = *(const float4*)(v + base + g);
    s16x4 hb; hb[0] = f2bf(a.x); hb[1] = f2bf(a.y); hb[2] = f2bf(a.z); hb[3] = f2bf(a.w);
    *(s16x4*)&Vb[row * 132 + col] = hb;
  }
  __syncthreads();
#pragma unroll
  for (int it = 0; it < 4; ++it) {
    const int cid = it * 256 + t;
    const int d = cid >> 3, rc = (cid & 7) * 8;
    s16x8 o;
#pragma unroll
    for (int e = 0; e < 8; ++e) o[e] = (short)Vb[(rc + e) * 132 + d];
    *(s16x8*)&bhp[A_VT * AR + (size_t)d * kN + r0 + rc] = o;
  }
}

// ============================ main kernel ============================
// 2 blocks/CU (LDS ~75.8 KB, VGPR pinned <=64 by launch bounds) -> 8 waves/SIMD
// with cross-block phase diversity. Gram A-frags and PV B-frags read directly
// from ws (L2-hot, shared by the 16 same-bh blocks on an XCD).
__global__ __launch_bounds__(NTH, 8)
void cpka_ws(const unsigned short* __restrict__ wsu, const float* __restrict__ wsf,
             float* __restrict__ outp, float* __restrict__ attnp) {
  const int hw = blockIdx.x;
  const int lg = (hw & 7) * 128 + (hw >> 3);
  const int bh = lg >> 4;
  const int i0 = (lg & 15) * IT;
  const int t = threadIdx.x;
  const int lane = t & 63;
  const int w = t >> 6;
  const int l15 = lane & 15, l4 = lane >> 4;
  const int wjf = w & 3;                // j-frag 0..3
  const int wip = w >> 2;               // i-frag 0..3

  __shared__ unsigned short Qhi[IT * SI];
  __shared__ unsigned short Kii[IT * SI];
  __shared__ unsigned short Sqi[IT * SI];
  __shared__ unsigned short PreT[IT * SPT];
  __shared__ float s_qn2[kN], s_kn2[kN], s_sks[kN];   // full-N row stats
  __shared__ float s_sqsi[IT];
  __shared__ float s_part[4][IT];
  __shared__ float s_invn[IT];

  const unsigned short* bhp = wsu + (size_t)bh * BHU;
  float* attb = attnp + (size_t)bh * kN * kN;
  float* outb = outp + (size_t)bh * kN * kD;

  // ---- stage i-side bf16 + full-N stats ----
  const int srow = t >> 4, sc8 = (t & 15) * 8;
  {
    const size_t g = (size_t)(i0 + srow) * kD + sc8;
    *(s16x8*)&Qhi[srow * SI + sc8] = *(const s16x8*)&bhp[A_QH * AR + g];
    *(s16x8*)&Sqi[srow * SI + sc8] = *(const s16x8*)&bhp[A_SQ * AR + g];
    *(s16x8*)&Kii[srow * SI + sc8] = *(const s16x8*)&bhp[A_KR * AR + g];
    s_qn2[t] = wsf[0 * KBN + bh * kN + t];
    s_kn2[t] = wsf[1 * KBN + bh * kN + t];
    s_sks[t] = wsf[3 * KBN + bh * kN + t];
    if (t < IT) s_sqsi[t] = wsf[2 * KBN + bh * kN + i0 + t];
  }
  __syncthreads();

  f32x4 oacc[2];
#pragma unroll
  for (int np = 0; np < 2; ++np) oacc[np] = (f32x4){0.f, 0.f, 0.f, 0.f};
  float rowss = 0.f;
  s16x4 pk_all[16];

  // per-wave global operand bases
  const size_t arow_el = (size_t)(wjf * 16 + l15) * kD + l4 * 8;   // + j0*kD per tile
  const size_t vrow0 = A_VT * AR + (size_t)(wjf * 32 + l15) * kN + l4 * 8;
  const size_t vrow1 = A_VT * AR + (size_t)(wjf * 32 + 16 + l15) * kN + l4 * 8;
  const int brow = (wip * 16 + l15) * SI + l4 * 8;

#pragma unroll
  for (int jt = 0; jt < 16; ++jt) {
    const int j0 = jt * JT;
    const size_t jrow = arow_el + (size_t)j0 * kD;

    // ---- grams: A from global (L2-hot), B from i-side LDS ----
    f32x4 acos = (f32x4){0.f, 0.f, 0.f, 0.f};
    f32x4 ase  = (f32x4){0.f, 0.f, 0.f, 0.f};
    f32x4 as1  = (f32x4){0.f, 0.f, 0.f, 0.f};
#pragma unroll
    for (int ks = 0; ks < 4; ++ks) {
      const s16x8 aKh = *(const s16x8*)&bhp[A_KH * AR + jrow + ks * 32];
      const s16x8 aQj = *(const s16x8*)&bhp[A_QR * AR + jrow + ks * 32];
      const s16x8 aSk = *(const s16x8*)&bhp[A_SK * AR + jrow + ks * 32];
      const int bo = brow + ks * 32;
      acos = __builtin_amdgcn_mfma_f32_16x16x32_bf16(aKh, *(const s16x8*)&Qhi[bo], acos, 0, 0, 0);
      ase  = __builtin_amdgcn_mfma_f32_16x16x32_bf16(aQj, *(const s16x8*)&Kii[bo], ase, 0, 0, 0);
      as1  = __builtin_amdgcn_mfma_f32_16x16x32_bf16(aSk, *(const s16x8*)&Sqi[bo], as1, 0, 0, 0);
    }

    // ---- PV B-frags from global (issued early; epilogue covers latency) ----
    const s16x8 vB00 = *(const s16x8*)&bhp[vrow0 + j0];        // ks2=0, np=0
    const s16x8 vB10 = *(const s16x8*)&bhp[vrow0 + j0 + 32];   // ks2=1, np=0
    const s16x8 vB01 = *(const s16x8*)&bhp[vrow1 + j0];        // ks2=0, np=1
    const s16x8 vB11 = *(const s16x8*)&bhp[vrow1 + j0 + 32];   // ks2=1, np=1

    // ---- epilogue ----
    {
      const int iloc = wip * 16 + l15;
      const float kn2i = s_kn2[i0 + iloc], qn2i = s_qn2[i0 + iloc];
      const float sqsi = s_sqsi[iloc];
      s16x4 pk;
#pragma unroll
      for (int r = 0; r < 4; ++r) {
        const int jloc = j0 + wjf * 16 + l4 * 4 + r;
        const float kq = ase[r];    // q_j . k_i (index-crossed SE term)
        const float cs = acos[r];
        const float s1 = as1[r];
        const float se = -sqrtf(fmaxf(kn2i + s_qn2[jloc] - 2.0f * kq, 0.f)) * INV2SD;
        const float rev = sqrtf(fmaxf(TWOA - 2.0f * cs, 0.f));
        const float per = (__builtin_amdgcn_cosf(rev) - 1.0f) * INVSD;
        const float Bc = 128.0f - sqsi - s_sks[jloc] + s1;
        const float p = s1 * __expf(se) + Bc * __expf(per)
                        + (qn2i + s_kn2[jloc]) * INV2SD;
        rowss += p * p;
        pk[r] = (short)f2bf(p);
      }
      pk_all[jt] = pk;
      __syncthreads();   // A: PV(jt-1) PreT readers done
      *(s16x4*)&PreT[iloc * SPT + wjf * 16 + l4 * 4] = pk;
    }
    __syncthreads();     // B: PreT(jt) visible

    // ---- PV: A from PreT (LDS), B from regs ----
    {
      const s16x8 A0 = *(const s16x8*)&PreT[(wip * 16 + l15) * SPT + l4 * 8];
      const s16x8 A1 = *(const s16x8*)&PreT[(wip * 16 + l15) * SPT + 32 + l4 * 8];
      oacc[0] = __builtin_amdgcn_mfma_f32_16x16x32_bf16(A0, vB00, oacc[0], 0, 0, 0);
      oacc[1] = __builtin_amdgcn_mfma_f32_16x16x32_bf16(A0, vB01, oacc[1], 0, 0, 0);
      oacc[0] = __builtin_amdgcn_mfma_f32_16x16x32_bf16(A1, vB10, oacc[0], 0, 0, 0);
      oacc[1] = __builtin_amdgcn_mfma_f32_16x16x32_bf16(A1, vB11, oacc[1], 0, 0, 0);
    }
  }

  // ---- row L2 norm ----
  {
    float rsv = rowss;
    rsv += __shfl_xor(rsv, 16);
    rsv += __shfl_xor(rsv, 32);
    if (l4 == 0) s_part[wjf][wip * 16 + l15] = rsv;
  }
  __syncthreads();
  if (t < IT) {
    const float ssum = s_part[0][t] + s_part[1][t] + s_part[2][t] + s_part[3][t];
    s_invn[t] = 1.0f / fmaxf(sqrtf(ssum), 1e-12f);
  }
  __syncthreads();

  // ---- out = (pre @ vals) * invn ----
#pragma unroll
  for (int np = 0; np < 2; ++np)
#pragma unroll
    for (int r = 0; r < 4; ++r) {
      const int iloc = wip * 16 + l4 * 4 + r;
      const int d = wjf * 32 + np * 16 + l15;
      outb[(size_t)(i0 + iloc) * kD + d] = oacc[np][r] * s_invn[iloc];
    }

  // ---- attn: normalized, coalesced via PreT bounce ----
#pragma unroll
  for (int jt = 0; jt < 16; ++jt) {
    __syncthreads();   // prior PreT readers done
    *(s16x4*)&PreT[(wip * 16 + l15) * SPT + wjf * 16 + l4 * 4] = pk_all[jt];
    __syncthreads();
    const int row = t >> 4, col = (t & 15) * 4;
    const s16x4 hv = *(const s16x4*)&PreT[row * SPT + col];
    const float inv = s_invn[row];
    f32x4 w0;
    w0[0] = bf2f((unsigned short)hv[0]) * inv;
    w0[1] = bf2f((unsigned short)hv[1]) * inv;
    w0[2] = bf2f((unsigned short)hv[2]) * inv;
    w0[3] = bf2f((unsigned short)hv[3]) * inv;
    __builtin_nontemporal_store(
        w0, (f32x4*)(attb + (size_t)(i0 + row) * kN + jt * JT + col));
  }
}

}  // namespace

extern "C" void kernel_launch(void* const* d_in, const int* in_sizes, int n_in,
                              void* d_out, int out_size, void* d_ws, size_t ws_size,
                              hipStream_t stream) {
  (void)in_sizes; (void)n_in; (void)out_size; (void)ws_size;
  const float* q = (const float*)d_in[0];
  const float* k = (const float*)d_in[1];
  const float* v = (const float*)d_in[2];
  float* outp = (float*)d_out;
  float* attnp = outp + (size_t)kBH * kN * kD;
  unsigned short* wsu = (unsigned short*)d_ws;
  float* wsf = (float*)d_ws + FOFF;

  cpka_prep<<<dim3(kBH * 16), 256, 0, stream>>>(q, k, v, wsu, wsf);
  cpka_ws<<<dim3(kBH * (kN / IT)), NTH, 0, stream>>>(wsu, wsf, outp, attnp);
}

// Round 13
// 274.015 us; speedup vs baseline: 2.2541x; 2.2541x over previous
//
#include <hip/hip_runtime.h>
#include <math.h>

namespace {

constexpr int kN = 1024;
constexpr int kD = 128;
constexpr int kBH = 64;
constexpr int IT = 64;     // i rows per block
constexpr int JT = 64;     // j cols per tile
constexpr int NTH = 1024;  // 16 waves
constexpr int SI = 144;    // i-side LDS row stride (bf16) — 16-slot bank spread
constexpr int SJ = 144;    // j-side LDS row stride
constexpr int SPT = 80;    // per-tile Pre stride

constexpr float INV2SD = 0.04419417382415922f;  // 1/(2*sqrt(128))
constexpr float INVSD  = 0.08838834764831843f;  // 1/sqrt(128)
constexpr float TWOA   = 2.0f + 1e-5f;

// ws layout (u16 region then f32 region)
constexpr size_t AR = (size_t)kN * kD;
constexpr size_t BHU = 7 * AR;
constexpr size_t WS_U16 = (size_t)kBH * BHU;
constexpr size_t FOFF = WS_U16 / 2;
constexpr int KBN = kBH * kN;
constexpr int A_QH = 0, A_SQ = 1, A_QR = 2, A_KH = 3, A_SK = 4, A_KR = 5, A_VT = 6;

typedef __attribute__((ext_vector_type(8))) short s16x8;
typedef __attribute__((ext_vector_type(4))) short s16x4;
typedef __attribute__((ext_vector_type(4))) float f32x4;

__device__ __forceinline__ unsigned short f2bf(float f) {
  unsigned u = __float_as_uint(f);
  u += 0x7fffu + ((u >> 16) & 1u);   // RNE
  return (unsigned short)(u >> 16);
}
__device__ __forceinline__ float bf2f(unsigned short b) {
  return __uint_as_float(((unsigned)b) << 16);
}
// fast hw sigmoid: v_exp + v_rcp (1 ulp each; bf16 rounding dominates)
__device__ __forceinline__ float sigm(float x) {
  return __builtin_amdgcn_rcpf(1.0f + __expf(-x));
}

__device__ __forceinline__ int vswz(int jblk, int d) {
  return (jblk ^ (d & 7) ^ ((d >> 4) & 7)) << 3;
}

// ============================ prep kernel ============================
__global__ __launch_bounds__(256, 2)
void cpka_prep(const float* __restrict__ q, const float* __restrict__ k,
               const float* __restrict__ v, unsigned short* __restrict__ wsu,
               float* __restrict__ wsf) {
  const int blk = blockIdx.x;
  const int bh = blk >> 4;
  const int r0 = (blk & 15) * 64;
  const int t = threadIdx.x;
  unsigned short* bhp = wsu + (size_t)bh * BHU;
  const size_t base = ((size_t)bh * kN + r0) * kD;

  __shared__ unsigned short Vb[64 * 132];

#pragma unroll
  for (int pass = 0; pass < 2; ++pass) {
    const float* src = (pass == 0 ? q : k) + base;
    const int aH = (pass == 0) ? A_QH : A_KH;
    const int aS = (pass == 0) ? A_SQ : A_SK;
    const int aR = (pass == 0) ? A_QR : A_KR;
    const int sN = (pass == 0) ? 0 : 1;
    const int sS = (pass == 0) ? 2 : 3;
#pragma unroll 2
    for (int it = 0; it < 8; ++it) {
      const int g = it * 1024 + t * 4;
      const int row = g >> 7;
      const float4 a = *(const float4*)(src + g);
      float ss = a.x * a.x + a.y * a.y + a.z * a.z + a.w * a.w;
      ss += __shfl_xor(ss, 1); ss += __shfl_xor(ss, 2); ss += __shfl_xor(ss, 4);
      ss += __shfl_xor(ss, 8); ss += __shfl_xor(ss, 16);
      const float rn = __builtin_amdgcn_rsqf(ss);
      const float x0 = a.x * rn, x1 = a.y * rn, x2 = a.z * rn, x3 = a.w * rn;
      s16x4 hb; hb[0] = f2bf(x0); hb[1] = f2bf(x1); hb[2] = f2bf(x2); hb[3] = f2bf(x3);
      *(s16x4*)&bhp[aH * AR + (size_t)r0 * kD + g] = hb;
      const float g0 = sigm(x0), g1 = sigm(x1), g2 = sigm(x2), g3 = sigm(x3);
      float sg = g0 + g1 + g2 + g3;
      sg += __shfl_xor(sg, 1); sg += __shfl_xor(sg, 2); sg += __shfl_xor(sg, 4);
      sg += __shfl_xor(sg, 8); sg += __shfl_xor(sg, 16);
      s16x4 sb; sb[0] = f2bf(g0); sb[1] = f2bf(g1); sb[2] = f2bf(g2); sb[3] = f2bf(g3);
      *(s16x4*)&bhp[aS * AR + (size_t)r0 * kD + g] = sb;
      s16x4 rb; rb[0] = f2bf(a.x); rb[1] = f2bf(a.y); rb[2] = f2bf(a.z); rb[3] = f2bf(a.w);
      *(s16x4*)&bhp[aR * AR + (size_t)r0 * kD + g] = rb;
      if ((t & 31) == 0) {
        wsf[sN * KBN + bh * kN + r0 + row] = ss;
        wsf[sS * KBN + bh * kN + r0 + row] = sg;
      }
    }
  }

#pragma unroll 2
  for (int it = 0; it < 8; ++it) {
    const int g = it * 1024 + t * 4;
    const int row = g >> 7, col = g & 127;
    const float4 a = *(const float4*)(v + base + g);
    s16x4 hb; hb[0] = f2bf(a.x); hb[1] = f2bf(a.y); hb[2] = f2bf(a.z); hb[3] = f2bf(a.w);
    *(s16x4*)&Vb[row * 132 + col] = hb;
  }
  __syncthreads();
#pragma unroll
  for (int it = 0; it < 4; ++it) {
    const int cid = it * 256 + t;
    const int d = cid >> 3, rc = (cid & 7) * 8;
    s16x8 o;
#pragma unroll
    for (int e = 0; e < 8; ++e) o[e] = (short)Vb[(rc + e) * 132 + d];
    *(s16x8*)&bhp[A_VT * AR + (size_t)d * kN + r0 + rc] = o;
  }
}

// ============================ main kernel ============================
__global__ __launch_bounds__(NTH, 4)
void cpka_ws(const unsigned short* __restrict__ wsu, const float* __restrict__ wsf,
             float* __restrict__ outp, float* __restrict__ attnp) {
  const int hw = blockIdx.x;
  const int lg = (hw & 7) * 128 + (hw >> 3);
  const int bh = lg >> 4;
  const int i0 = (lg & 15) * IT;
  const int t = threadIdx.x;
  const int lane = t & 63;
  const int w = t >> 6;
  const int l15 = lane & 15, l4 = lane >> 4;
  const int wjf = w & 3;                // j-frag 0..3
  const int wip = w >> 2;               // i-frag 0..3

  __shared__ unsigned short Qhi[IT * SI];
  __shared__ unsigned short Kii[IT * SI];
  __shared__ unsigned short Sqi[IT * SI];
  __shared__ unsigned short Khj[JT * SJ];
  __shared__ unsigned short Qjj[JT * SJ];
  __shared__ unsigned short Skj[JT * SJ];
  __shared__ unsigned short Vt[2][kD * 64];   // double-buffered V^T tile
  __shared__ unsigned short PreT[IT * SPT];
  __shared__ float s_qn2i[IT], s_kn2i[IT], s_sqsi[IT];
  __shared__ float s_qn2j[JT], s_kn2j[JT], s_sksj[JT];
  __shared__ float s_part[4][IT];
  __shared__ float s_invn[IT];

  const unsigned short* bhp = wsu + (size_t)bh * BHU;
  float* attb = attnp + (size_t)bh * kN * kN;
  float* outb = outp + (size_t)bh * kN * kD;

  // ---- i-side: bf16 copies + scalars ----
  const int srow = t >> 4, sc8 = (t & 15) * 8;
  {
    const size_t g = (size_t)(i0 + srow) * kD + sc8;
    *(s16x8*)&Qhi[srow * SI + sc8] = *(const s16x8*)&bhp[A_QH * AR + g];
    *(s16x8*)&Sqi[srow * SI + sc8] = *(const s16x8*)&bhp[A_SQ * AR + g];
    *(s16x8*)&Kii[srow * SI + sc8] = *(const s16x8*)&bhp[A_KR * AR + g];
    if (t < 64)       s_qn2i[t] = wsf[0 * KBN + bh * kN + i0 + t];
    else if (t < 128) s_kn2i[t - 64] = wsf[1 * KBN + bh * kN + i0 + (t - 64)];
    else if (t < 192) s_sqsi[t - 128] = wsf[2 * KBN + bh * kN + i0 + (t - 128)];
  }

  // ---- prefetch + stage tile 0, prefetch tile 1 ----
  const int vd = t >> 3, vjc = (t & 7) * 8;
  s16x8 pKh = *(const s16x8*)&bhp[A_KH * AR + (size_t)srow * kD + sc8];
  s16x8 pQj = *(const s16x8*)&bhp[A_QR * AR + (size_t)srow * kD + sc8];
  s16x8 pSk = *(const s16x8*)&bhp[A_SK * AR + (size_t)srow * kD + sc8];
  s16x8 pVt = *(const s16x8*)&bhp[A_VT * AR + (size_t)vd * kN + vjc];
  float pstat = 0.f;
  if (t < 64)       pstat = wsf[0 * KBN + bh * kN + t];
  else if (t < 128) pstat = wsf[1 * KBN + bh * kN + (t - 64)];
  else if (t < 192) pstat = wsf[3 * KBN + bh * kN + (t - 128)];

  *(s16x8*)&Khj[srow * SJ + sc8] = pKh;
  *(s16x8*)&Qjj[srow * SJ + sc8] = pQj;
  *(s16x8*)&Skj[srow * SJ + sc8] = pSk;
  *(s16x8*)&Vt[0][vd * 64 + vswz(vjc >> 3, vd)] = pVt;
  if (t < 64)       s_qn2j[t] = pstat;
  else if (t < 128) s_kn2j[t - 64] = pstat;
  else if (t < 192) s_sksj[t - 128] = pstat;

  {
    const int jn = JT;
    pKh = *(const s16x8*)&bhp[A_KH * AR + (size_t)(jn + srow) * kD + sc8];
    pQj = *(const s16x8*)&bhp[A_QR * AR + (size_t)(jn + srow) * kD + sc8];
    pSk = *(const s16x8*)&bhp[A_SK * AR + (size_t)(jn + srow) * kD + sc8];
    pVt = *(const s16x8*)&bhp[A_VT * AR + (size_t)vd * kN + jn + vjc];
    if (t < 64)       pstat = wsf[0 * KBN + bh * kN + jn + t];
    else if (t < 128) pstat = wsf[1 * KBN + bh * kN + jn + (t - 64)];
    else if (t < 192) pstat = wsf[3 * KBN + bh * kN + jn + (t - 128)];
  }
  __syncthreads();   // A: tile 0 staged

  f32x4 oacc[2];
#pragma unroll
  for (int np = 0; np < 2; ++np) oacc[np] = (f32x4){0.f, 0.f, 0.f, 0.f};
  float rowss = 0.f;
  s16x4 pk_all[16];

#pragma unroll
  for (int jt = 0; jt < 16; ++jt) {
    // ---- grams (P^T: a = j-side, b = i-side) ----
    f32x4 acos = (f32x4){0.f, 0.f, 0.f, 0.f};
    f32x4 ase  = (f32x4){0.f, 0.f, 0.f, 0.f};
    f32x4 as1  = (f32x4){0.f, 0.f, 0.f, 0.f};
    const int arow = (wjf * 16 + l15) * SJ + l4 * 8;
    const int brow = (wip * 16 + l15) * SI + l4 * 8;
#pragma unroll
    for (int ks = 0; ks < 4; ++ks) {
      const int ao = arow + ks * 32;
      const int bo = brow + ks * 32;
      acos = __builtin_amdgcn_mfma_f32_16x16x32_bf16(
          *(const s16x8*)&Khj[ao], *(const s16x8*)&Qhi[bo], acos, 0, 0, 0);
      ase  = __builtin_amdgcn_mfma_f32_16x16x32_bf16(
          *(const s16x8*)&Qjj[ao], *(const s16x8*)&Kii[bo], ase, 0, 0, 0);
      as1  = __builtin_amdgcn_mfma_f32_16x16x32_bf16(
          *(const s16x8*)&Skj[ao], *(const s16x8*)&Sqi[bo], as1, 0, 0, 0);
    }

    // ---- epilogue (fast hw sqrt: 1 inst vs ~12 for IEEE sqrtf) ----
    {
      const int iloc = wip * 16 + l15;
      const float kn2i = s_kn2i[iloc], qn2i = s_qn2i[iloc], sqsi = s_sqsi[iloc];
      s16x4 pk;
#pragma unroll
      for (int r = 0; r < 4; ++r) {
        const int jloc = wjf * 16 + l4 * 4 + r;
        const float kq = ase[r];    // q_j . k_i (index-crossed SE term)
        const float cs = acos[r];
        const float s1 = as1[r];
        const float se =
            -__builtin_amdgcn_sqrtf(fmaxf(kn2i + s_qn2j[jloc] - 2.0f * kq, 0.f)) * INV2SD;
        const float rev = __builtin_amdgcn_sqrtf(fmaxf(TWOA - 2.0f * cs, 0.f));
        const float per = (__builtin_amdgcn_cosf(rev) - 1.0f) * INVSD;
        const float Bc = 128.0f - sqsi - s_sksj[jloc] + s1;
        const float p = s1 * __expf(se) + Bc * __expf(per)
                        + (qn2i + s_kn2j[jloc]) * INV2SD;
        rowss += p * p;
        pk[r] = (short)f2bf(p);
      }
      pk_all[jt] = pk;
      *(s16x4*)&PreT[iloc * SPT + wjf * 16 + l4 * 4] = pk;
    }
    __syncthreads();   // B: PreT + staged j-side visible

    // ---- PV (reads PreT + Vt[jt&1]) ----
#pragma unroll
    for (int ks2 = 0; ks2 < 2; ++ks2) {
      const s16x8 A = *(const s16x8*)&PreT[(wip * 16 + l15) * SPT + ks2 * 32 + l4 * 8];
#pragma unroll
      for (int np = 0; np < 2; ++np) {
        const int d = wjf * 32 + np * 16 + l15;
        const s16x8 B = *(const s16x8*)&Vt[jt & 1][d * 64 + vswz(ks2 * 4 + l4, d)];
        oacc[np] = __builtin_amdgcn_mfma_f32_16x16x32_bf16(A, B, oacc[np], 0, 0, 0);
      }
    }

    // ---- stage tile jt+1 ----
    if (jt < 15) {
      *(s16x8*)&Khj[srow * SJ + sc8] = pKh;
      *(s16x8*)&Qjj[srow * SJ + sc8] = pQj;
      *(s16x8*)&Skj[srow * SJ + sc8] = pSk;
      *(s16x8*)&Vt[(jt + 1) & 1][vd * 64 + vswz(vjc >> 3, vd)] = pVt;
      if (t < 64)       s_qn2j[t] = pstat;
      else if (t < 128) s_kn2j[t - 64] = pstat;
      else if (t < 192) s_sksj[t - 128] = pstat;
      if (jt < 14) {
        const int jn = (jt + 2) * JT;
        pKh = *(const s16x8*)&bhp[A_KH * AR + (size_t)(jn + srow) * kD + sc8];
        pQj = *(const s16x8*)&bhp[A_QR * AR + (size_t)(jn + srow) * kD + sc8];
        pSk = *(const s16x8*)&bhp[A_SK * AR + (size_t)(jn + srow) * kD + sc8];
        pVt = *(const s16x8*)&bhp[A_VT * AR + (size_t)vd * kN + jn + vjc];
        if (t < 64)       pstat = wsf[0 * KBN + bh * kN + jn + t];
        else if (t < 128) pstat = wsf[1 * KBN + bh * kN + jn + (t - 64)];
        else if (t < 192) pstat = wsf[3 * KBN + bh * kN + jn + (t - 128)];
      }
      __syncthreads();   // A: tile jt+1 staged
    }
  }

  // ---- row L2 norm ----
  {
    float rsv = rowss;
    rsv += __shfl_xor(rsv, 16);
    rsv += __shfl_xor(rsv, 32);
    if (l4 == 0) s_part[wjf][wip * 16 + l15] = rsv;
  }
  __syncthreads();
  if (t < IT) {
    const float ssum = s_part[0][t] + s_part[1][t] + s_part[2][t] + s_part[3][t];
    s_invn[t] = 1.0f / fmaxf(sqrtf(ssum), 1e-12f);
  }
  __syncthreads();

  // ---- out = (pre @ vals) * invn ----
#pragma unroll
  for (int np = 0; np < 2; ++np)
#pragma unroll
    for (int r = 0; r < 4; ++r) {
      const int iloc = wip * 16 + l4 * 4 + r;
      const int d = wjf * 32 + np * 16 + l15;
      outb[(size_t)(i0 + iloc) * kD + d] = oacc[np][r] * s_invn[iloc];
    }

  // ---- attn: normalized, coalesced via double-buffered LDS bounce ----
#pragma unroll
  for (int jt = 0; jt < 16; ++jt) {
    unsigned short* tb = &Vt[jt & 1][0];
    *(s16x4*)&tb[(wip * 16 + l15) * SPT + wjf * 16 + l4 * 4] = pk_all[jt];
    __syncthreads();
    const int row = t >> 4, col = (t & 15) * 4;
    const s16x4 hv = *(const s16x4*)&tb[row * SPT + col];
    const float inv = s_invn[row];
    f32x4 w0;
    w0[0] = bf2f((unsigned short)hv[0]) * inv;
    w0[1] = bf2f((unsigned short)hv[1]) * inv;
    w0[2] = bf2f((unsigned short)hv[2]) * inv;
    w0[3] = bf2f((unsigned short)hv[3]) * inv;
    __builtin_nontemporal_store(
        w0, (f32x4*)(attb + (size_t)(i0 + row) * kN + jt * JT + col));
  }
}

}  // namespace

extern "C" void kernel_launch(void* const* d_in, const int* in_sizes, int n_in,
                              void* d_out, int out_size, void* d_ws, size_t ws_size,
                              hipStream_t stream) {
  (void)in_sizes; (void)n_in; (void)out_size; (void)ws_size;
  const float* q = (const float*)d_in[0];
  const float* k = (const float*)d_in[1];
  const float* v = (const float*)d_in[2];
  float* outp = (float*)d_out;
  float* attnp = outp + (size_t)kBH * kN * kD;
  unsigned short* wsu = (unsigned short*)d_ws;
  float* wsf = (float*)d_ws + FOFF;

  cpka_prep<<<dim3(kBH * 16), 256, 0, stream>>>(q, k, v, wsu, wsf);
  cpka_ws<<<dim3(kBH * (kN / IT)), NTH, 0, stream>>>(wsu, wsf, outp, attnp);
}